// Round 4
// baseline (250.266 us; speedup 1.0000x reference)
//
#include <hip/hip_runtime.h>
#include <cstdint>
#include <cstddef>

#define B_ 4
#define L_ 4096
#define E_ 1024
#define H_ 16
#define D_ 64
#define BH_ (B_*H_)
#define STATE_ (65*64)   // rows 0..63 = kv[d][e], row 64 = ksum[d]

__device__ __forceinline__ float sigk(float x) {
    // sigmoid(0.6053*x - 4.102) = 1/(1+exp(4.102 - 0.6053*x))
    return __builtin_amdgcn_rcpf(1.0f + __expf(4.102f - 0.6053f * x));
}

// XOR swizzle on float4-index within a 1024-f4 region: spreads the 8x8
// per-lane fragment stores across all 8 LDS bank-groups (else 16-way).
__device__ __forceinline__ int swz(int f4) {
    return f4 ^ ((f4 >> 7) & 7);
}

// ---------------- Kernel 1: partial KV state per (b,h,chunk) ----------------
// 1024 blocks (4/CU), 33 KB LDS, 4 waves. Each wave computes the full 64x64
// outer product (8x8/lane) over its private 16-row range of each 64-row tile;
// reg-staged prefetch hides HBM under compute; LDS tree-reduce merges waves.
__global__ void __launch_bounds__(256, 4) kv_partial_kernel(
    const float* __restrict__ K, const float* __restrict__ V,
    float* __restrict__ partial, int nch, int rowsPerCh)
{
    __shared__ float lds[8192 + 256];
    float* Kt = lds;            // 64 x 64 phi(K)
    float* Vt = lds + 4096;     // 64 x 64 V

    const int ch = blockIdx.x % nch;
    const int bh = blockIdx.x / nch;
    const int b = bh / H_, h = bh % H_;
    const int tid = threadIdx.x;
    const int w = tid >> 6, lane = tid & 63;
    const int rr = tid >> 4, c4 = (tid & 15) << 2;   // staging row-group, col
    const int d0 = (lane >> 3) << 3;                 // 8 d's per lane
    const int e0 = (lane & 7) << 3;                  // 8 e's per lane
    const int cb = e0 >> 2;                          // f4 col base

    const size_t gbase = (size_t)(b * L_ + ch * rowsPerCh) * E_ + h * D_ + c4;
    const int nr = rowsPerCh >> 6;

    float4 kreg[4], vreg[4];
    float acc[8][8];
    #pragma unroll
    for (int i = 0; i < 8; ++i)
        #pragma unroll
        for (int j = 0; j < 8; ++j) acc[i][j] = 0.f;
    float ks[8] = {0.f,0.f,0.f,0.f,0.f,0.f,0.f,0.f};

    // prologue: round-0 loads
    #pragma unroll
    for (int i = 0; i < 4; ++i) {
        const size_t g = gbase + (size_t)(rr + (i << 4)) * E_;
        kreg[i] = *(const float4*)(K + g);
        vreg[i] = *(const float4*)(V + g);
    }

    for (int t = 0; t < nr; ++t) {
        #pragma unroll
        for (int i = 0; i < 4; ++i) {
            const int row = rr + (i << 4);
            float4 pk;
            pk.x = sigk(kreg[i].x); pk.y = sigk(kreg[i].y);
            pk.z = sigk(kreg[i].z); pk.w = sigk(kreg[i].w);
            *(float4*)(Kt + (row << 6) + c4) = pk;
            *(float4*)(Vt + (row << 6) + c4) = vreg[i];
        }
        __syncthreads();
        if (t + 1 < nr) {   // issue next round's loads; land during compute
            #pragma unroll
            for (int i = 0; i < 4; ++i) {
                const size_t g = gbase +
                    (size_t)(((t + 1) << 6) + rr + (i << 4)) * E_;
                kreg[i] = *(const float4*)(K + g);
                vreg[i] = *(const float4*)(V + g);
            }
        }
        // compute over this wave's 16-row k-range (reads are row-uniform
        // broadcasts -> conflict-free, 4 b128 per 64 FMA)
        const float* kp = Kt + ((w << 4) << 6) + d0;
        const float* vp = Vt + ((w << 4) << 6) + e0;
        #pragma unroll 4
        for (int kk = 0; kk < 16; ++kk) {
            const float4 ka0 = *(const float4*)(kp);
            const float4 ka1 = *(const float4*)(kp + 4);
            const float4 vb0 = *(const float4*)(vp);
            const float4 vb1 = *(const float4*)(vp + 4);
            const float av[8] = {ka0.x,ka0.y,ka0.z,ka0.w,ka1.x,ka1.y,ka1.z,ka1.w};
            const float bv[8] = {vb0.x,vb0.y,vb0.z,vb0.w,vb1.x,vb1.y,vb1.z,vb1.w};
            #pragma unroll
            for (int i = 0; i < 8; ++i)
                #pragma unroll
                for (int j = 0; j < 8; ++j)
                    acc[i][j] = fmaf(av[i], bv[j], acc[i][j]);
            if (e0 == 0) {
                #pragma unroll
                for (int i = 0; i < 8; ++i) ks[i] += av[i];
            }
            kp += 64; vp += 64;
        }
        __syncthreads();
    }

    // ---- inter-wave tree reduce (regions of 4096 floats, swizzled) ----
    if (w >= 2) {
        float* reg0 = lds + ((w - 2) << 12);
        #pragma unroll
        for (int i = 0; i < 8; ++i) {
            const int f4 = ((d0 + i) << 4) + cb;
            *(float4*)(reg0 + (swz(f4) << 2)) =
                make_float4(acc[i][0], acc[i][1], acc[i][2], acc[i][3]);
            *(float4*)(reg0 + (swz(f4 + 1) << 2)) =
                make_float4(acc[i][4], acc[i][5], acc[i][6], acc[i][7]);
        }
        if (e0 == 0) {
            #pragma unroll
            for (int i = 0; i < 8; ++i)
                lds[8192 + ((w - 2) << 6) + d0 + i] = ks[i];
        }
    }
    __syncthreads();
    if (w < 2) {
        float* reg0 = lds + (w << 12);
        #pragma unroll
        for (int i = 0; i < 8; ++i) {
            const int f4 = ((d0 + i) << 4) + cb;
            const float4 p0 = *(const float4*)(reg0 + (swz(f4) << 2));
            const float4 p1 = *(const float4*)(reg0 + (swz(f4 + 1) << 2));
            acc[i][0] += p0.x; acc[i][1] += p0.y;
            acc[i][2] += p0.z; acc[i][3] += p0.w;
            acc[i][4] += p1.x; acc[i][5] += p1.y;
            acc[i][6] += p1.z; acc[i][7] += p1.w;
        }
        if (e0 == 0) {
            #pragma unroll
            for (int i = 0; i < 8; ++i) ks[i] += lds[8192 + (w << 6) + d0 + i];
        }
    }
    __syncthreads();
    if (w == 1) {
        float* reg0 = lds;
        #pragma unroll
        for (int i = 0; i < 8; ++i) {
            const int f4 = ((d0 + i) << 4) + cb;
            *(float4*)(reg0 + (swz(f4) << 2)) =
                make_float4(acc[i][0], acc[i][1], acc[i][2], acc[i][3]);
            *(float4*)(reg0 + (swz(f4 + 1) << 2)) =
                make_float4(acc[i][4], acc[i][5], acc[i][6], acc[i][7]);
        }
        if (e0 == 0) {
            #pragma unroll
            for (int i = 0; i < 8; ++i) lds[8192 + 128 + d0 + i] = ks[i];
        }
    }
    __syncthreads();
    if (w == 0) {
        float* reg0 = lds;
        #pragma unroll
        for (int i = 0; i < 8; ++i) {
            const int f4 = ((d0 + i) << 4) + cb;
            const int a0 = swz(f4) << 2, a1 = swz(f4 + 1) << 2;
            const float4 p0 = *(const float4*)(reg0 + a0);
            const float4 p1 = *(const float4*)(reg0 + a1);
            *(float4*)(reg0 + a0) =
                make_float4(acc[i][0] + p0.x, acc[i][1] + p0.y,
                            acc[i][2] + p0.z, acc[i][3] + p0.w);
            *(float4*)(reg0 + a1) =
                make_float4(acc[i][4] + p1.x, acc[i][5] + p1.y,
                            acc[i][6] + p1.z, acc[i][7] + p1.w);
        }
        if (e0 == 0) {
            #pragma unroll
            for (int i = 0; i < 8; ++i)
                lds[8192 + 192 + d0 + i] = ks[i] + lds[8192 + 128 + d0 + i];
        }
    }
    __syncthreads();

    // coalesced block-partial store
    const size_t pbase = ((size_t)ch * BH_ + bh) * (size_t)STATE_;
    #pragma unroll
    for (int it = 0; it < 4; ++it) {
        const int f4 = tid + (it << 8);
        const float4 v = *(const float4*)(lds + (swz(f4) << 2));
        *(float4*)(partial + pbase + ((size_t)f4 << 2)) = v;
    }
    if (tid < 64) partial[pbase + 4096 + tid] = lds[8192 + 192 + tid];
}

// ---------------- Kernel 2: reduce partials -> final KV state ----------------
__global__ void __launch_bounds__(256) kv_reduce_kernel(
    const float* __restrict__ partial, float* __restrict__ kv, int nch)
{
    const int total = BH_ * STATE_;
    const int idx = blockIdx.x * 256 + threadIdx.x;
    if (idx >= total) return;
    float s = 0.f;
    for (int c = 0; c < nch; ++c) s += partial[(size_t)c * total + idx];
    kv[idx] = s;
}

// ---------------- Kernel 3: out = (phiQ @ kv) / (phiQ @ ksum) ----------------
__global__ void __launch_bounds__(256) attn_out_kernel(
    const float* __restrict__ Q, const float* __restrict__ kv,
    float* __restrict__ out)
{
    __shared__ float kvs[STATE_];
    const int bh = blockIdx.x >> 6;          // 64 q-tiles of 64 rows per (b,h)
    const int qt = blockIdx.x & 63;
    const int b = bh / H_, h = bh % H_;
    const int tid = threadIdx.x;
    {
        const float4* src = (const float4*)(kv + (size_t)bh * STATE_);
        float4* dst = (float4*)kvs;
        for (int i = tid; i < STATE_ / 4; i += 256) dst[i] = src[i];
    }
    __syncthreads();

    const int rq  = tid >> 2;            // 0..63: q-row within tile
    const int el  = (tid & 3) << 2;      // 0,4,8,12: e sub-offset
    const int row = qt * 64 + rq;
    const float4* qp = (const float4*)(Q + ((size_t)b * L_ + row) * E_ + h * D_);

    float4 acc[4];
    #pragma unroll
    for (int j = 0; j < 4; ++j) acc[j] = make_float4(0.f, 0.f, 0.f, 0.f);
    float den = 0.f;

    #pragma unroll 4
    for (int jj = 0; jj < 16; ++jj) {
        const float4 a = qp[jj];
        const float p[4] = {sigk(a.x), sigk(a.y), sigk(a.z), sigk(a.w)};
        const int dbase = jj << 2;
        #pragma unroll
        for (int i = 0; i < 4; ++i) {
            const float s = p[i];
            den = fmaf(s, kvs[4096 + dbase + i], den);
            const float* krow = kvs + (size_t)(dbase + i) * 64 + el;
            #pragma unroll
            for (int j = 0; j < 4; ++j) {
                const float4 v = *(const float4*)(krow + (j << 4));
                acc[j].x = fmaf(s, v.x, acc[j].x);
                acc[j].y = fmaf(s, v.y, acc[j].y);
                acc[j].z = fmaf(s, v.z, acc[j].z);
                acc[j].w = fmaf(s, v.w, acc[j].w);
            }
        }
    }

    const float inv = __builtin_amdgcn_rcpf(den);
    float* op = out + ((size_t)b * L_ + row) * E_ + h * D_ + el;
    #pragma unroll
    for (int j = 0; j < 4; ++j) {
        float4 o;
        o.x = acc[j].x * inv; o.y = acc[j].y * inv;
        o.z = acc[j].z * inv; o.w = acc[j].w * inv;
        *(float4*)(op + (j << 4)) = o;
    }
}

extern "C" void kernel_launch(void* const* d_in, const int* in_sizes, int n_in,
                              void* d_out, int out_size, void* d_ws, size_t ws_size,
                              hipStream_t stream) {
    const float* Q = (const float*)d_in[0];
    const float* K = (const float*)d_in[1];
    const float* V = (const float*)d_in[2];
    float* out = (float*)d_out;

    float* kv      = (float*)d_ws;                 // BH_*STATE_ floats (~1 MiB)
    float* partial = kv + (size_t)BH_ * STATE_;    // nch*BH_*STATE_ floats

    int nch = 16;
    while (nch > 1 &&
           (size_t)(1 + nch) * BH_ * STATE_ * sizeof(float) > ws_size)
        nch >>= 1;
    const int rowsPerCh = L_ / nch;

    hipLaunchKernelGGL(kv_partial_kernel, dim3(BH_ * nch), dim3(256), 0, stream,
                       K, V, partial, nch, rowsPerCh);

    const int total = BH_ * STATE_;
    hipLaunchKernelGGL(kv_reduce_kernel, dim3((total + 255) / 256), dim3(256), 0, stream,
                       partial, kv, nch);

    hipLaunchKernelGGL(attn_out_kernel, dim3(BH_ * (L_ / 64)), dim3(256), 0, stream,
                       Q, kv, out);
}

// Round 5
// 129.154 us; speedup vs baseline: 1.9377x; 1.9377x over previous
//
#include <hip/hip_runtime.h>
#include <cstdint>
#include <cstddef>

#define B_ 4
#define L_ 4096
#define E_ 1024
#define H_ 16
#define D_ 64
#define BH_ (B_*H_)
#define STATE_ (65*64)   // rows 0..63 = kv[d][e], row 64 = ksum[d]

__device__ __forceinline__ float sigk(float x) {
    // sigmoid(0.6053*x - 4.102) = 1/(1+exp(4.102 - 0.6053*x))
    return __builtin_amdgcn_rcpf(1.0f + __expf(4.102f - 0.6053f * x));
}

// XOR swizzle on float4-index within a 1024-f4 region: spreads the 8x8
// per-lane fragment stores across all 8 LDS bank-groups (else 16-way).
__device__ __forceinline__ int swz(int f4) {
    return f4 ^ ((f4 >> 7) & 7);
}

// ---------------- Kernel 1: partial KV state per (b,h,chunk) ----------------
// 1024 blocks, 33 KB LDS, 4 waves. Each wave computes the full 64x64 outer
// product (8x8/lane) over its private 16-row range of each 64-row tile;
// reg-staged prefetch hides HBM under compute; LDS tree-reduce merges waves.
// NO min-waves launch bound: forcing 4 blocks/CU (round 4) made the compiler
// cram ~115 live regs into 64 -> scratch spills (FETCH +38MB, WRITE +340MB).
__global__ void __launch_bounds__(256) kv_partial_kernel(
    const float* __restrict__ K, const float* __restrict__ V,
    float* __restrict__ partial, int nch, int rowsPerCh)
{
    __shared__ float lds[8192 + 256];
    float* Kt = lds;            // 64 x 64 phi(K)
    float* Vt = lds + 4096;     // 64 x 64 V

    const int ch = blockIdx.x % nch;
    const int bh = blockIdx.x / nch;
    const int b = bh / H_, h = bh % H_;
    const int tid = threadIdx.x;
    const int w = tid >> 6, lane = tid & 63;
    const int rr = tid >> 4, c4 = (tid & 15) << 2;   // staging row-group, col
    const int d0 = (lane >> 3) << 3;                 // 8 d's per lane
    const int e0 = (lane & 7) << 3;                  // 8 e's per lane
    const int cb = e0 >> 2;                          // f4 col base

    const size_t gbase = (size_t)(b * L_ + ch * rowsPerCh) * E_ + h * D_ + c4;
    const int nr = rowsPerCh >> 6;

    float4 kreg[4], vreg[4];
    float acc[8][8];
    #pragma unroll
    for (int i = 0; i < 8; ++i)
        #pragma unroll
        for (int j = 0; j < 8; ++j) acc[i][j] = 0.f;
    float ks[8] = {0.f,0.f,0.f,0.f,0.f,0.f,0.f,0.f};

    // prologue: round-0 loads
    #pragma unroll
    for (int i = 0; i < 4; ++i) {
        const size_t g = gbase + (size_t)(rr + (i << 4)) * E_;
        kreg[i] = *(const float4*)(K + g);
        vreg[i] = *(const float4*)(V + g);
    }

    for (int t = 0; t < nr; ++t) {
        #pragma unroll
        for (int i = 0; i < 4; ++i) {
            const int row = rr + (i << 4);
            float4 pk;
            pk.x = sigk(kreg[i].x); pk.y = sigk(kreg[i].y);
            pk.z = sigk(kreg[i].z); pk.w = sigk(kreg[i].w);
            *(float4*)(Kt + (row << 6) + c4) = pk;
            *(float4*)(Vt + (row << 6) + c4) = vreg[i];
        }
        __syncthreads();
        if (t + 1 < nr) {   // issue next round's loads; land during compute
            #pragma unroll
            for (int i = 0; i < 4; ++i) {
                const size_t g = gbase +
                    (size_t)(((t + 1) << 6) + rr + (i << 4)) * E_;
                kreg[i] = *(const float4*)(K + g);
                vreg[i] = *(const float4*)(V + g);
            }
        }
        // compute over this wave's 16-row k-range (reads are 8-lane
        // broadcasts; distinct addrs are 2-per-bank = free)
        const float* kp = Kt + ((w << 4) << 6) + d0;
        const float* vp = Vt + ((w << 4) << 6) + e0;
        #pragma unroll 4
        for (int kk = 0; kk < 16; ++kk) {
            const float4 ka0 = *(const float4*)(kp);
            const float4 ka1 = *(const float4*)(kp + 4);
            const float4 vb0 = *(const float4*)(vp);
            const float4 vb1 = *(const float4*)(vp + 4);
            const float av[8] = {ka0.x,ka0.y,ka0.z,ka0.w,ka1.x,ka1.y,ka1.z,ka1.w};
            const float bv[8] = {vb0.x,vb0.y,vb0.z,vb0.w,vb1.x,vb1.y,vb1.z,vb1.w};
            #pragma unroll
            for (int i = 0; i < 8; ++i)
                #pragma unroll
                for (int j = 0; j < 8; ++j)
                    acc[i][j] = fmaf(av[i], bv[j], acc[i][j]);
            if (e0 == 0) {
                #pragma unroll
                for (int i = 0; i < 8; ++i) ks[i] += av[i];
            }
            kp += 64; vp += 64;
        }
        __syncthreads();
    }

    // ---- inter-wave tree reduce (regions of 4096 floats, swizzled) ----
    if (w >= 2) {
        float* reg0 = lds + ((w - 2) << 12);
        #pragma unroll
        for (int i = 0; i < 8; ++i) {
            const int f4 = ((d0 + i) << 4) + cb;
            *(float4*)(reg0 + (swz(f4) << 2)) =
                make_float4(acc[i][0], acc[i][1], acc[i][2], acc[i][3]);
            *(float4*)(reg0 + (swz(f4 + 1) << 2)) =
                make_float4(acc[i][4], acc[i][5], acc[i][6], acc[i][7]);
        }
        if (e0 == 0) {
            #pragma unroll
            for (int i = 0; i < 8; ++i)
                lds[8192 + ((w - 2) << 6) + d0 + i] = ks[i];
        }
    }
    __syncthreads();
    if (w < 2) {
        float* reg0 = lds + (w << 12);
        #pragma unroll
        for (int i = 0; i < 8; ++i) {
            const int f4 = ((d0 + i) << 4) + cb;
            const float4 p0 = *(const float4*)(reg0 + (swz(f4) << 2));
            const float4 p1 = *(const float4*)(reg0 + (swz(f4 + 1) << 2));
            acc[i][0] += p0.x; acc[i][1] += p0.y;
            acc[i][2] += p0.z; acc[i][3] += p0.w;
            acc[i][4] += p1.x; acc[i][5] += p1.y;
            acc[i][6] += p1.z; acc[i][7] += p1.w;
        }
        if (e0 == 0) {
            #pragma unroll
            for (int i = 0; i < 8; ++i) ks[i] += lds[8192 + (w << 6) + d0 + i];
        }
    }
    __syncthreads();
    if (w == 1) {
        float* reg0 = lds;
        #pragma unroll
        for (int i = 0; i < 8; ++i) {
            const int f4 = ((d0 + i) << 4) + cb;
            *(float4*)(reg0 + (swz(f4) << 2)) =
                make_float4(acc[i][0], acc[i][1], acc[i][2], acc[i][3]);
            *(float4*)(reg0 + (swz(f4 + 1) << 2)) =
                make_float4(acc[i][4], acc[i][5], acc[i][6], acc[i][7]);
        }
        if (e0 == 0) {
            #pragma unroll
            for (int i = 0; i < 8; ++i) lds[8192 + 128 + d0 + i] = ks[i];
        }
    }
    __syncthreads();
    if (w == 0) {
        float* reg0 = lds;
        #pragma unroll
        for (int i = 0; i < 8; ++i) {
            const int f4 = ((d0 + i) << 4) + cb;
            const int a0 = swz(f4) << 2, a1 = swz(f4 + 1) << 2;
            const float4 p0 = *(const float4*)(reg0 + a0);
            const float4 p1 = *(const float4*)(reg0 + a1);
            *(float4*)(reg0 + a0) =
                make_float4(acc[i][0] + p0.x, acc[i][1] + p0.y,
                            acc[i][2] + p0.z, acc[i][3] + p0.w);
            *(float4*)(reg0 + a1) =
                make_float4(acc[i][4] + p1.x, acc[i][5] + p1.y,
                            acc[i][6] + p1.z, acc[i][7] + p1.w);
        }
        if (e0 == 0) {
            #pragma unroll
            for (int i = 0; i < 8; ++i)
                lds[8192 + 192 + d0 + i] = ks[i] + lds[8192 + 128 + d0 + i];
        }
    }
    __syncthreads();

    // coalesced block-partial store
    const size_t pbase = ((size_t)ch * BH_ + bh) * (size_t)STATE_;
    #pragma unroll
    for (int it = 0; it < 4; ++it) {
        const int f4 = tid + (it << 8);
        const float4 v = *(const float4*)(lds + (swz(f4) << 2));
        *(float4*)(partial + pbase + ((size_t)f4 << 2)) = v;
    }
    if (tid < 64) partial[pbase + 4096 + tid] = lds[8192 + 192 + tid];
}

// ---------------- Kernel 2: reduce partials -> final KV state ----------------
__global__ void __launch_bounds__(256) kv_reduce_kernel(
    const float* __restrict__ partial, float* __restrict__ kv, int nch)
{
    const int total = BH_ * STATE_;
    const int idx = blockIdx.x * 256 + threadIdx.x;
    if (idx >= total) return;
    float s = 0.f;
    for (int c = 0; c < nch; ++c) s += partial[(size_t)c * total + idx];
    kv[idx] = s;
}

// ---------------- Kernel 3: out = (phiQ @ kv) / (phiQ @ ksum) ----------------
__global__ void __launch_bounds__(256) attn_out_kernel(
    const float* __restrict__ Q, const float* __restrict__ kv,
    float* __restrict__ out)
{
    __shared__ float kvs[STATE_];
    const int bh = blockIdx.x >> 6;          // 64 q-tiles of 64 rows per (b,h)
    const int qt = blockIdx.x & 63;
    const int b = bh / H_, h = bh % H_;
    const int tid = threadIdx.x;
    {
        const float4* src = (const float4*)(kv + (size_t)bh * STATE_);
        float4* dst = (float4*)kvs;
        for (int i = tid; i < STATE_ / 4; i += 256) dst[i] = src[i];
    }
    __syncthreads();

    const int rq  = tid >> 2;            // 0..63: q-row within tile
    const int el  = (tid & 3) << 2;      // 0,4,8,12: e sub-offset
    const int row = qt * 64 + rq;
    const float4* qp = (const float4*)(Q + ((size_t)b * L_ + row) * E_ + h * D_);

    float4 acc[4];
    #pragma unroll
    for (int j = 0; j < 4; ++j) acc[j] = make_float4(0.f, 0.f, 0.f, 0.f);
    float den = 0.f;

    #pragma unroll 4
    for (int jj = 0; jj < 16; ++jj) {
        const float4 a = qp[jj];
        const float p[4] = {sigk(a.x), sigk(a.y), sigk(a.z), sigk(a.w)};
        const int dbase = jj << 2;
        #pragma unroll
        for (int i = 0; i < 4; ++i) {
            const float s = p[i];
            den = fmaf(s, kvs[4096 + dbase + i], den);
            const float* krow = kvs + (size_t)(dbase + i) * 64 + el;
            #pragma unroll
            for (int j = 0; j < 4; ++j) {
                const float4 v = *(const float4*)(krow + (j << 4));
                acc[j].x = fmaf(s, v.x, acc[j].x);
                acc[j].y = fmaf(s, v.y, acc[j].y);
                acc[j].z = fmaf(s, v.z, acc[j].z);
                acc[j].w = fmaf(s, v.w, acc[j].w);
            }
        }
    }

    const float inv = __builtin_amdgcn_rcpf(den);
    float* op = out + ((size_t)b * L_ + row) * E_ + h * D_ + el;
    #pragma unroll
    for (int j = 0; j < 4; ++j) {
        float4 o;
        o.x = acc[j].x * inv; o.y = acc[j].y * inv;
        o.z = acc[j].z * inv; o.w = acc[j].w * inv;
        *(float4*)(op + (j << 4)) = o;
    }
}

extern "C" void kernel_launch(void* const* d_in, const int* in_sizes, int n_in,
                              void* d_out, int out_size, void* d_ws, size_t ws_size,
                              hipStream_t stream) {
    const float* Q = (const float*)d_in[0];
    const float* K = (const float*)d_in[1];
    const float* V = (const float*)d_in[2];
    float* out = (float*)d_out;

    float* kv      = (float*)d_ws;                 // BH_*STATE_ floats (~1 MiB)
    float* partial = kv + (size_t)BH_ * STATE_;    // nch*BH_*STATE_ floats

    int nch = 16;
    while (nch > 1 &&
           (size_t)(1 + nch) * BH_ * STATE_ * sizeof(float) > ws_size)
        nch >>= 1;
    const int rowsPerCh = L_ / nch;

    hipLaunchKernelGGL(kv_partial_kernel, dim3(BH_ * nch), dim3(256), 0, stream,
                       K, V, partial, nch, rowsPerCh);

    const int total = BH_ * STATE_;
    hipLaunchKernelGGL(kv_reduce_kernel, dim3((total + 255) / 256), dim3(256), 0, stream,
                       partial, kv, nch);

    hipLaunchKernelGGL(attn_out_kernel, dim3(BH_ * (L_ / 64)), dim3(256), 0, stream,
                       Q, kv, out);
}